// Round 3
// baseline (218.692 us; speedup 1.0000x reference)
//
#include <hip/hip_runtime.h>

#define STN 9
#define CC 3
#define HH 288
#define WW 288
#define KF 5
#define KK 25
#define OWN 96
#define NPIX 9216
#define TILE 16
#define OG 3                    // o's per block
#define PST 28                  // padded per-pixel weight stride in LDS (112B rows, 16B aligned)
#define LBUF (OG*TILE*PST)      // 1344 floats = 5376 B per wave
#define PLANE (HH*WW)
#define WCHUNK4 ((NPIX*KK)/4)   // float4 per (o,i) plane

__global__ __launch_bounds__(256, 4)
void lfk3(const float* __restrict__ lf, const float* __restrict__ wts,
          const float* __restrict__ bias, float* __restrict__ out)
{
    __shared__ float wl[4][LBUF];          // 21504 B total -> 7 blocks/CU
    const int tid  = threadIdx.x;
    const int wv   = tid >> 6;             // wave 0..3
    const int lane = tid & 63;
    const int tile = blockIdx.x / OG;
    const int og   = blockIdx.x - tile * OG;
    const int p0   = tile * TILE;
    const int pix  = lane & (TILE - 1);
    const int b    = lane >> 4;

    const int g  = p0 + pix;
    const int oh = g / OWN;
    const int ow = g - oh * OWN;
    const int y0 = oh * 3 - 2;             // pt = pl = 2, no bottom/right pad
    const int x0 = ow * 3 - 2;

    const float4* __restrict__ w4 = (const float4*)wts;
    float* const myl = wl[wv];

    // i-split: wave0 -> i=0,1,2 ; wave1 -> 3,4 ; wave2 -> 5,6 ; wave3 -> 7,8
    const int istart = (wv == 0) ? 0 : (wv * 2 + 1);
    const int icnt   = (wv == 0) ? 3 : 2;

    float4 r0, r1, r2, r3, r4;

    auto stage_load = [&](int i) {
        // 300 float4 per (og-group, i): chunk per o_local = 100 f4, contiguous
        #pragma unroll
        for (int j = 0; j < 5; ++j) {
            const int idx = lane + j * 64;
            if (j < 4 || idx < 300) {
                const int ol  = idx / 100;
                const int rem = idx - ol * 100;
                const float4 v = w4[((og * OG + ol) * STN + i) * WCHUNK4 + tile * 100 + rem];
                if (j == 0) r0 = v; else if (j == 1) r1 = v; else if (j == 2) r2 = v;
                else if (j == 3) r3 = v; else r4 = v;
            }
        }
    };
    auto stage_write = [&]() {
        #pragma unroll
        for (int j = 0; j < 5; ++j) {
            const int idx = lane + j * 64;
            if (j < 4 || idx < 300) {
                const int ol  = idx / 100;
                const int rem = idx - ol * 100;
                const int f0  = rem * 4;
                float4 v;
                if (j == 0) v = r0; else if (j == 1) v = r1; else if (j == 2) v = r2;
                else if (j == 3) v = r3; else v = r4;
                float vv[4] = {v.x, v.y, v.z, v.w};
                #pragma unroll
                for (int q = 0; q < 4; ++q) {
                    const int f  = f0 + q;
                    const int pd = f / 25;
                    const int k  = f - pd * 25;
                    myl[(ol * TILE + pd) * PST + k] = vv[q];
                }
            }
        }
    };

    float acc[OG][CC];
    #pragma unroll
    for (int oc = 0; oc < OG; ++oc)
        #pragma unroll
        for (int c = 0; c < CC; ++c) acc[oc][c] = 0.f;

    stage_load(istart);

    for (int s = 0; s < icnt; ++s) {
        const int i = istart + s;
        stage_write();
        if (s + 1 < icnt) stage_load(i + 1);   // prefetch next i into regs

        // ---- patches for (b, i, c=0..2) ----
        float p[CC][KK];
        if (y0 >= 0 && x0 >= 0) {
            #pragma unroll
            for (int c = 0; c < CC; ++c) {
                const float* lfb = lf + ((b * STN + i) * CC + c) * PLANE + y0 * WW + x0;
                #pragma unroll
                for (int kh = 0; kh < KF; ++kh)
                    #pragma unroll
                    for (int kw = 0; kw < KF; ++kw)
                        p[c][kh * KF + kw] = lfb[kh * WW + kw];
            }
        } else {
            #pragma unroll
            for (int c = 0; c < CC; ++c) {
                const float* lfb = lf + ((b * STN + i) * CC + c) * PLANE;
                #pragma unroll
                for (int kh = 0; kh < KF; ++kh) {
                    const int y = y0 + kh;
                    #pragma unroll
                    for (int kw = 0; kw < KF; ++kw) {
                        const int x = x0 + kw;
                        p[c][kh * KF + kw] = (y >= 0 && x >= 0) ? lfb[y * WW + x] : 0.f;
                    }
                }
            }
        }

        // ---- contraction from this wave's LDS region (112B-aligned rows) ----
        #pragma unroll
        for (int oc = 0; oc < OG; ++oc) {
            const float* wrow = myl + (oc * TILE + pix) * PST;
            float w[KK];
            #pragma unroll
            for (int k = 0; k < KK; ++k) w[k] = wrow[k];
            #pragma unroll
            for (int c = 0; c < CC; ++c)
                #pragma unroll
                for (int k = 0; k < KK; ++k)
                    acc[oc][c] = fmaf(w[k], p[c][k], acc[oc][c]);
        }
    }

    // ---- cross-wave reduction: waves 1-3 park partials in their own region ----
    if (wv != 0) {
        #pragma unroll
        for (int oc = 0; oc < OG; ++oc)
            #pragma unroll
            for (int c = 0; c < CC; ++c)
                myl[lane * 9 + oc * CC + c] = acc[oc][c];
    }
    __syncthreads();

    if (wv == 0) {
        #pragma unroll
        for (int w = 1; w < 4; ++w)
            #pragma unroll
            for (int oc = 0; oc < OG; ++oc)
                #pragma unroll
                for (int c = 0; c < CC; ++c)
                    acc[oc][c] += wl[w][lane * 9 + oc * CC + c];

        #pragma unroll
        for (int oc = 0; oc < OG; ++oc) {
            const int o = og * OG + oc;
            const float bo = bias[o * NPIX + g];
            #pragma unroll
            for (int c = 0; c < CC; ++c) {
                float v = acc[oc][c] + bo;
                v = fminf(fmaxf(v, 0.f), 1.f);
                out[((b * STN + o) * CC + c) * NPIX + g] = v;
            }
        }
    }
}

extern "C" void kernel_launch(void* const* d_in, const int* in_sizes, int n_in,
                              void* d_out, int out_size, void* d_ws, size_t ws_size,
                              hipStream_t stream) {
    const float* lf   = (const float*)d_in[0];
    const float* wts  = (const float*)d_in[1];
    const float* bias = (const float*)d_in[2];
    float* out = (float*)d_out;
    (void)d_ws; (void)ws_size; (void)in_sizes; (void)n_in; (void)out_size;

    dim3 grid((NPIX / TILE) * OG);   // 1728 blocks x 4 waves = 6912 waves
    dim3 block(256);
    lfk3<<<grid, block, 0, stream>>>(lf, wts, bias, out);
}

// Round 4
// 53.527 us; speedup vs baseline: 4.0856x; 4.0856x over previous
//
#include <hip/hip_runtime.h>

#define STN 9
#define CC 3
#define HH 288
#define WW 288
#define KF 5
#define KK 25
#define OWN 96
#define NPIX 9216
#define TILE 16
#define OG 3                    // o's per block
#define PST 28                  // padded per-pixel weight stride in LDS (112B rows, 16B aligned)
#define LBUF (OG*TILE*PST)      // 1344 floats = 5376 B per wave
#define PLANE (HH*WW)
#define WCHUNK4 ((NPIX*KK)/4)   // float4 per (o,i) plane

// NOTE: no min-waves clause — (256,4) forced a 64-VGPR allocation with ~430MB
// of scratch spill traffic (R3). Kernel needs ~135 live VGPRs.
__global__ __launch_bounds__(256)
void lfk4(const float* __restrict__ lf, const float* __restrict__ wts,
          const float* __restrict__ bias, float* __restrict__ out)
{
    __shared__ float wl[4][LBUF];          // 21504 B total
    const int tid  = threadIdx.x;
    const int wv   = tid >> 6;             // wave 0..3
    const int lane = tid & 63;
    const int tile = blockIdx.x / OG;
    const int og   = blockIdx.x - tile * OG;
    const int p0   = tile * TILE;
    const int pix  = lane & (TILE - 1);
    const int b    = lane >> 4;

    const int g  = p0 + pix;
    const int oh = g / OWN;
    const int ow = g - oh * OWN;
    const int y0 = oh * 3 - 2;             // pt = pl = 2, no bottom/right pad
    const int x0 = ow * 3 - 2;

    const float4* __restrict__ w4 = (const float4*)wts;
    float* const myl = wl[wv];

    // i-split: wave0 -> i=0,1,2 ; wave1 -> 3,4 ; wave2 -> 5,6 ; wave3 -> 7,8
    const int istart = (wv == 0) ? 0 : (wv * 2 + 1);
    const int icnt   = (wv == 0) ? 3 : 2;

    float4 r0, r1, r2, r3, r4;

    auto stage_load = [&](int i) {
        // 300 float4 per (og-group, i): chunk per o_local = 100 f4, contiguous
        #pragma unroll
        for (int j = 0; j < 5; ++j) {
            const int idx = lane + j * 64;
            if (j < 4 || idx < 300) {
                const int ol  = idx / 100;
                const int rem = idx - ol * 100;
                const float4 v = w4[((og * OG + ol) * STN + i) * WCHUNK4 + tile * 100 + rem];
                if (j == 0) r0 = v; else if (j == 1) r1 = v; else if (j == 2) r2 = v;
                else if (j == 3) r3 = v; else r4 = v;
            }
        }
    };
    auto stage_write = [&]() {
        #pragma unroll
        for (int j = 0; j < 5; ++j) {
            const int idx = lane + j * 64;
            if (j < 4 || idx < 300) {
                const int ol  = idx / 100;
                const int rem = idx - ol * 100;
                const int f0  = rem * 4;
                float4 v;
                if (j == 0) v = r0; else if (j == 1) v = r1; else if (j == 2) v = r2;
                else if (j == 3) v = r3; else v = r4;
                float vv[4] = {v.x, v.y, v.z, v.w};
                #pragma unroll
                for (int q = 0; q < 4; ++q) {
                    const int f  = f0 + q;
                    const int pd = f / 25;
                    const int k  = f - pd * 25;
                    myl[(ol * TILE + pd) * PST + k] = vv[q];
                }
            }
        }
    };

    float acc[OG][CC];
    #pragma unroll
    for (int oc = 0; oc < OG; ++oc)
        #pragma unroll
        for (int c = 0; c < CC; ++c) acc[oc][c] = 0.f;

    stage_load(istart);

    for (int s = 0; s < icnt; ++s) {
        const int i = istart + s;
        stage_write();
        if (s + 1 < icnt) stage_load(i + 1);   // prefetch next i into regs

        // ---- patches for (b, i, c=0..2) ----
        float p[CC][KK];
        if (y0 >= 0 && x0 >= 0) {
            #pragma unroll
            for (int c = 0; c < CC; ++c) {
                const float* lfb = lf + ((b * STN + i) * CC + c) * PLANE + y0 * WW + x0;
                #pragma unroll
                for (int kh = 0; kh < KF; ++kh)
                    #pragma unroll
                    for (int kw = 0; kw < KF; ++kw)
                        p[c][kh * KF + kw] = lfb[kh * WW + kw];
            }
        } else {
            #pragma unroll
            for (int c = 0; c < CC; ++c) {
                const float* lfb = lf + ((b * STN + i) * CC + c) * PLANE;
                #pragma unroll
                for (int kh = 0; kh < KF; ++kh) {
                    const int y = y0 + kh;
                    #pragma unroll
                    for (int kw = 0; kw < KF; ++kw) {
                        const int x = x0 + kw;
                        p[c][kh * KF + kw] = (y >= 0 && x >= 0) ? lfb[y * WW + x] : 0.f;
                    }
                }
            }
        }

        // ---- contraction from this wave's LDS region (112B-aligned rows) ----
        #pragma unroll
        for (int oc = 0; oc < OG; ++oc) {
            const float* wrow = myl + (oc * TILE + pix) * PST;
            float w[KK];
            #pragma unroll
            for (int k = 0; k < KK; ++k) w[k] = wrow[k];
            #pragma unroll
            for (int c = 0; c < CC; ++c)
                #pragma unroll
                for (int k = 0; k < KK; ++k)
                    acc[oc][c] = fmaf(w[k], p[c][k], acc[oc][c]);
        }
    }

    // ---- cross-wave reduction: waves 1-3 park partials in their own region ----
    if (wv != 0) {
        #pragma unroll
        for (int oc = 0; oc < OG; ++oc)
            #pragma unroll
            for (int c = 0; c < CC; ++c)
                myl[lane * 9 + oc * CC + c] = acc[oc][c];
    }
    __syncthreads();

    if (wv == 0) {
        #pragma unroll
        for (int w = 1; w < 4; ++w)
            #pragma unroll
            for (int oc = 0; oc < OG; ++oc)
                #pragma unroll
                for (int c = 0; c < CC; ++c)
                    acc[oc][c] += wl[w][lane * 9 + oc * CC + c];

        #pragma unroll
        for (int oc = 0; oc < OG; ++oc) {
            const int o = og * OG + oc;
            const float bo = bias[o * NPIX + g];
            #pragma unroll
            for (int c = 0; c < CC; ++c) {
                float v = acc[oc][c] + bo;
                v = fminf(fmaxf(v, 0.f), 1.f);
                out[((b * STN + o) * CC + c) * NPIX + g] = v;
            }
        }
    }
}

extern "C" void kernel_launch(void* const* d_in, const int* in_sizes, int n_in,
                              void* d_out, int out_size, void* d_ws, size_t ws_size,
                              hipStream_t stream) {
    const float* lf   = (const float*)d_in[0];
    const float* wts  = (const float*)d_in[1];
    const float* bias = (const float*)d_in[2];
    float* out = (float*)d_out;
    (void)d_ws; (void)ws_size; (void)in_sizes; (void)n_in; (void)out_size;

    dim3 grid((NPIX / TILE) * OG);   // 1728 blocks x 4 waves = 6912 waves
    dim3 block(256);
    lfk4<<<grid, block, 0, stream>>>(lf, wts, bias, out);
}

// Round 5
// 47.207 us; speedup vs baseline: 4.6326x; 1.1339x over previous
//
#include <hip/hip_runtime.h>

#define STN 9
#define CC 3
#define OWN 96
#define NPIX 9216
#define TILE 16
#define OG 3
#define PST 28            // padded weight row stride (floats)
#define RSP 56            // patch row span (floats) = 14 float4
#define NROWS 60          // 4b * 3c * 5kh
#define PLANE4 20736      // 288*288/4
#define ROW4 72           // 288/4
#define ISTEP4 62208      // 3*PLANE4 : f4 step per i in lf
#define LF_F4_LIM 2239488 // total lf floats / 4
#define WCH4 57600        // f4 per (o,i) weight plane
#define WISTEP4 57600
#define WOSTEP4 518400    // 9*57600

__global__ __launch_bounds__(192)
void lfk5(const float* __restrict__ lf, const float* __restrict__ wts,
          const float* __restrict__ bias, float* __restrict__ out)
{
    __shared__ float ldsP[NROWS * RSP];     // 3360 f = 13.44 KB
    __shared__ float ldsW[OG * TILE * PST]; // 1344 f =  5.38 KB

    const int tid = threadIdx.x;
    // XCD-bijective swizzle (1728 % 8 == 0): og-triples + neighbor tiles same XCD
    const int bid = blockIdx.x;
    const int swz = (bid & 7) * 216 + (bid >> 3);
    const int tile = swz / 3;
    const int og   = swz - tile * 3;
    const int oh   = tile / 6;
    const int tc   = tile - oh * 6;         // tile column 0..5
    const int pix  = tid & 15;
    const int bcq  = tid >> 4;              // 0..11
    const int b    = bcq / 3;
    const int c    = bcq - b * 3;
    const int y0   = oh * 3 - 2;            // pt = pl = 2
    const int xa4  = tc * 12 - 1;           // aligned f4 x-origin of staged rows
    const int g    = tile * 16 + pix;

    const float4* __restrict__ lf4 = (const float4*)lf;
    const float4* __restrict__ w4  = (const float4*)wts;

    // ---- precompute i-independent staging descriptors ----
    // patches: 840 f4 = 60 rows x 14 f4, over 192 threads (5 iters)
    int  pQ[5];          // LDS float offset (write target), -1 if none
    int  pG[5];          // lf f4 offset minus i*ISTEP4
    bool pL[5];          // load valid (in-bounds left/top)
    #pragma unroll
    for (int j = 0; j < 5; ++j) {
        const int idx = tid + 192 * j;
        pQ[j] = -1; pG[j] = 0; pL[j] = false;
        if (idx < 840) {
            const int row = idx / 14, jj = idx - row * 14;
            const int bb  = row / 15, r2 = row - bb * 15;
            const int cc  = r2 / 5,   kh = r2 - cc * 5;
            const int y   = y0 + kh;
            const int xs4 = xa4 + jj;
            pQ[j] = row * RSP + jj * 4;
            if (y >= 0 && xs4 >= 0) {
                pG[j] = (bb * 27 + cc) * PLANE4 + y * ROW4 + xs4;
                pL[j] = true;
            }
        }
    }
    // weights: 300 f4 = 3 o x 100 f4, over 192 threads (2 iters)
    int  wG[2]; int wL[2][4]; bool wV[2];
    #pragma unroll
    for (int j = 0; j < 2; ++j) {
        const int idx = tid + 192 * j;
        wV[j] = (idx < 300);
        wG[j] = 0; wL[j][0]=wL[j][1]=wL[j][2]=wL[j][3]=0;
        if (wV[j]) {
            const int ol = idx / 100, rem = idx - ol * 100;
            wG[j] = (og * 3 + ol) * WOSTEP4 + tile * 100 + rem;
            const int f0 = rem * 4;
            #pragma unroll
            for (int q = 0; q < 4; ++q) {
                const int f = f0 + q, pd = f / 25, k = f - pd * 25;
                wL[j][q] = (ol * TILE + pd) * PST + k;
            }
        }
    }

    float4 pr[5]; float4 wr[2];
    auto load_regs = [&](int i) {
        #pragma unroll
        for (int j = 0; j < 5; ++j) {
            float4 v = make_float4(0.f, 0.f, 0.f, 0.f);
            if (pL[j]) {
                const int gf4 = pG[j] + i * ISTEP4;
                if (gf4 < LF_F4_LIM) v = lf4[gf4];
            }
            pr[j] = v;
        }
        #pragma unroll
        for (int j = 0; j < 2; ++j)
            if (wV[j]) wr[j] = w4[wG[j] + i * WISTEP4];
    };
    auto store_lds = [&]() {
        #pragma unroll
        for (int j = 0; j < 5; ++j)
            if (pQ[j] >= 0) *(float4*)&ldsP[pQ[j]] = pr[j];
        #pragma unroll
        for (int j = 0; j < 2; ++j)
            if (wV[j]) {
                ldsW[wL[j][0]] = wr[j].x; ldsW[wL[j][1]] = wr[j].y;
                ldsW[wL[j][2]] = wr[j].z; ldsW[wL[j][3]] = wr[j].w;
            }
    };

    float acc[OG] = {0.f, 0.f, 0.f};
    const float* pbase = &ldsP[(b * 3 + c) * 5 * RSP + 2 + pix * 3];

    load_regs(0);
    for (int i = 0; i < STN; ++i) {
        __syncthreads();                 // prior compute done, LDS reusable
        store_lds();
        if (i < STN - 1) load_regs(i + 1);  // overlap HBM latency with compute
        __syncthreads();                 // staged data visible

        float p[25];
        #pragma unroll
        for (int kh = 0; kh < 5; ++kh)
            #pragma unroll
            for (int kw = 0; kw < 5; ++kw)
                p[kh * 5 + kw] = pbase[kh * RSP + kw];

        #pragma unroll
        for (int oc = 0; oc < OG; ++oc) {
            const float* wrow = &ldsW[(oc * TILE + pix) * PST];
            #pragma unroll
            for (int k = 0; k < 25; ++k)
                acc[oc] = fmaf(wrow[k], p[k], acc[oc]);
        }
    }

    #pragma unroll
    for (int oc = 0; oc < OG; ++oc) {
        const int o = og * 3 + oc;
        float v = acc[oc] + bias[o * NPIX + g];
        v = fminf(fmaxf(v, 0.f), 1.f);
        out[((b * STN + o) * CC + c) * NPIX + g] = v;
    }
}

extern "C" void kernel_launch(void* const* d_in, const int* in_sizes, int n_in,
                              void* d_out, int out_size, void* d_ws, size_t ws_size,
                              hipStream_t stream) {
    const float* lf   = (const float*)d_in[0];
    const float* wts  = (const float*)d_in[1];
    const float* bias = (const float*)d_in[2];
    float* out = (float*)d_out;
    (void)d_ws; (void)ws_size; (void)in_sizes; (void)n_in; (void)out_size;

    dim3 grid(576 * OG);    // 1728 blocks x 3 waves
    dim3 block(192);
    lfk5<<<grid, block, 0, stream>>>(lf, wts, bias, out);
}